// Round 1
// baseline (1595.990 us; speedup 1.0000x reference)
//
#include <hip/hip_runtime.h>
#include <hip/hip_bf16.h>

#define N_NODES 50000
#define N_EDGES 1600000
#define IN_FEAT 128
#define OUT_FEAT 32
#define NHEAD 4
#define HF 128            // NHEAD * OUT_FEAT
#define ALPHA 0.2f

// ---------------------------------------------------------------------------
// Kernel 1: h_all[n][h*32+f] = sum_k x[n][k] * W[h][k][f]
//           ssrc[n][h] = sum_f h*a_src[h][f] ; sdst likewise.
// One block (128 threads) per node. x row staged in LDS; W reads are
// coalesced (32 consecutive lanes -> 128B) and L2-resident (64 KB total).
// ---------------------------------------------------------------------------
__global__ __launch_bounds__(128) void gat_gemm_scores(
    const float* __restrict__ x,
    const float* __restrict__ W,       // [4][128][32]
    const float* __restrict__ a_src,   // [4][32]
    const float* __restrict__ a_dst,   // [4][32]
    float* __restrict__ h_all,         // [N][128]
    float* __restrict__ ssrc,          // [N][4]
    float* __restrict__ sdst)          // [N][4]
{
    const int n = blockIdx.x;
    const int t = threadIdx.x;     // 0..127
    const int head = t >> 5;
    const int f = t & 31;

    __shared__ float xrow[IN_FEAT];
    xrow[t] = x[(size_t)n * IN_FEAT + t];
    __syncthreads();

    const float* Wh = W + head * IN_FEAT * OUT_FEAT + f;
    float acc = 0.f;
#pragma unroll
    for (int k = 0; k < IN_FEAT; ++k)
        acc = fmaf(xrow[k], Wh[k * OUT_FEAT], acc);

    h_all[(size_t)n * HF + t] = acc;

    // per-head score reduction over the 32 feature lanes
    float vs = acc * a_src[head * OUT_FEAT + f];
    float vd = acc * a_dst[head * OUT_FEAT + f];
#pragma unroll
    for (int off = 16; off > 0; off >>= 1) {
        vs += __shfl_down(vs, off, 32);
        vd += __shfl_down(vd, off, 32);
    }
    if (f == 0) {
        ssrc[n * NHEAD + head] = vs;
        sdst[n * NHEAD + head] = vd;
    }
}

// ---------------------------------------------------------------------------
// Kernel 2: one wave per edge (grid-stride). For edge (s -> d):
//   w[h] = exp(leakyrelu(ssrc[s][h] + sdst[d][h]))
//   out[d][h*32+f] += w[h] * h_all[s][h*32+f]   (atomic)
//   denom[d][h]    += w[h]                      (atomic, 1 lane per head)
// Lane l covers features 2l, 2l+1 (both within head l>>4).
// No segment-max needed: scores are bounded (|e| < ~3), exp() cannot
// overflow, and softmax is shift-invariant.
// ---------------------------------------------------------------------------
__global__ __launch_bounds__(256) void gat_edge(
    const int* __restrict__ src,
    const int* __restrict__ dst,
    const float* __restrict__ h_all,
    const float* __restrict__ ssrc,
    const float* __restrict__ sdst,
    float* __restrict__ out_acc,       // [N][128] (d_out, pre-zeroed)
    float* __restrict__ denom)         // [N][4]   (pre-zeroed)
{
    const int lane = threadIdx.x & 63;
    const int wave = (blockIdx.x * blockDim.x + threadIdx.x) >> 6;
    const int nwave = (gridDim.x * blockDim.x) >> 6;
    const int head = lane >> 4;

    for (int e = wave; e < N_EDGES; e += nwave) {
        const int s = src[e];
        const int d = dst[e];

        float es = ssrc[s * NHEAD + head] + sdst[d * NHEAD + head];
        float lr = es > 0.f ? es : ALPHA * es;
        float w = __expf(lr);

        const float2 h2 = *reinterpret_cast<const float2*>(
            h_all + (size_t)s * HF + lane * 2);

        float* op = out_acc + (size_t)d * HF + lane * 2;
        atomicAdd(op,     w * h2.x);
        atomicAdd(op + 1, w * h2.y);

        if ((lane & 15) == 0)
            atomicAdd(denom + d * NHEAD + head, w);
    }
}

// ---------------------------------------------------------------------------
// Kernel 3: out = elu(out / denom), in place. denom==0 (isolated node) -> 0.
// ---------------------------------------------------------------------------
__global__ __launch_bounds__(256) void gat_finalize(
    float* __restrict__ out,
    const float* __restrict__ denom)
{
    const int i = blockIdx.x * blockDim.x + threadIdx.x;
    if (i >= N_NODES * HF) return;
    const int n = i >> 7;          // /128
    const int f = i & 127;
    const int head = f >> 5;
    const float dn = denom[n * NHEAD + head];
    float v = (dn > 0.f) ? out[i] / dn : 0.f;
    out[i] = v > 0.f ? v : expm1f(v);
}

// ---------------------------------------------------------------------------
extern "C" void kernel_launch(void* const* d_in, const int* in_sizes, int n_in,
                              void* d_out, int out_size, void* d_ws, size_t ws_size,
                              hipStream_t stream)
{
    const float* x     = (const float*)d_in[0];
    const int*   ei    = (const int*)d_in[1];   // [2][E] int32
    const float* W     = (const float*)d_in[2];
    const float* a_src = (const float*)d_in[3];
    const float* a_dst = (const float*)d_in[4];
    float* out = (float*)d_out;

    char* ws = (char*)d_ws;
    float* h_all = (float*)(ws);                          // 25,600,000 B
    float* ssrc  = (float*)(ws + 25600000);               //    800,000 B
    float* sdst  = (float*)(ws + 26400000);               //    800,000 B
    float* denom = (float*)(ws + 27200000);               //    800,000 B

    const int* src = ei;
    const int* dst = ei + N_EDGES;

    hipMemsetAsync(out,   0, (size_t)N_NODES * HF * sizeof(float), stream);
    hipMemsetAsync(denom, 0, (size_t)N_NODES * NHEAD * sizeof(float), stream);

    gat_gemm_scores<<<N_NODES, IN_FEAT, 0, stream>>>(
        x, W, a_src, a_dst, h_all, ssrc, sdst);

    gat_edge<<<2048, 256, 0, stream>>>(
        src, dst, h_all, ssrc, sdst, out, denom);

    gat_finalize<<<(N_NODES * HF + 255) / 256, 256, 0, stream>>>(out, denom);
}

// Round 3
// 682.679 us; speedup vs baseline: 2.3378x; 2.3378x over previous
//
#include <hip/hip_runtime.h>
#include <hip/hip_bf16.h>

#define N_NODES 50000
#define N_EDGES 1600000
#define IN_FEAT 128
#define OUT_FEAT 32
#define NHEAD 4
#define HF 128            // NHEAD * OUT_FEAT
#define ALPHA 0.2f

// ---------------------------------------------------------------------------
// Kernel 1: h_all[n][h*32+f] = sum_k x[n][k] * W[h][k][f]
//           ssrc[n][h] = (h . a_src[h]) ; sdst likewise.
// One block (128 threads) per node.
// ---------------------------------------------------------------------------
__global__ __launch_bounds__(128) void gat_gemm_scores(
    const float* __restrict__ x,
    const float* __restrict__ W,       // [4][128][32]
    const float* __restrict__ a_src,   // [4][32]
    const float* __restrict__ a_dst,   // [4][32]
    float* __restrict__ h_all,         // [N][128]
    float* __restrict__ ssrc,          // [N][4]
    float* __restrict__ sdst)          // [N][4]
{
    const int n = blockIdx.x;
    const int t = threadIdx.x;     // 0..127
    const int head = t >> 5;
    const int f = t & 31;

    __shared__ float xrow[IN_FEAT];
    xrow[t] = x[(size_t)n * IN_FEAT + t];
    __syncthreads();

    const float* Wh = W + head * IN_FEAT * OUT_FEAT + f;
    float acc = 0.f;
#pragma unroll
    for (int k = 0; k < IN_FEAT; ++k)
        acc = fmaf(xrow[k], Wh[k * OUT_FEAT], acc);

    h_all[(size_t)n * HF + t] = acc;

    float vs = acc * a_src[head * OUT_FEAT + f];
    float vd = acc * a_dst[head * OUT_FEAT + f];
#pragma unroll
    for (int off = 16; off > 0; off >>= 1) {
        vs += __shfl_down(vs, off, 32);
        vd += __shfl_down(vd, off, 32);
    }
    if (f == 0) {
        ssrc[n * NHEAD + head] = vs;
        sdst[n * NHEAD + head] = vd;
    }
}

// ---------------------------------------------------------------------------
// CSR build: histogram of dst -> exclusive scan -> scatter src ids.
// ---------------------------------------------------------------------------
__global__ __launch_bounds__(256) void edge_hist(
    const int* __restrict__ dst, int* __restrict__ cnt)
{
    for (int e = blockIdx.x * blockDim.x + threadIdx.x; e < N_EDGES;
         e += gridDim.x * blockDim.x)
        atomicAdd(&cnt[dst[e]], 1);
}

__global__ __launch_bounds__(256) void scan_offsets(
    const int* __restrict__ cnt, int* __restrict__ offs)
{
    __shared__ int tmp[256];
    __shared__ int carry;
    const int t = threadIdx.x;
    if (t == 0) carry = 0;
    __syncthreads();
    for (int base = 0; base < N_NODES; base += 256) {
        int v = (base + t < N_NODES) ? cnt[base + t] : 0;
        tmp[t] = v;
        __syncthreads();
#pragma unroll
        for (int off = 1; off < 256; off <<= 1) {
            int add = (t >= off) ? tmp[t - off] : 0;
            __syncthreads();
            tmp[t] += add;
            __syncthreads();
        }
        const int incl = tmp[t];
        const int c = carry;
        if (base + t < N_NODES) offs[base + t] = c + incl - v;  // exclusive
        __syncthreads();
        if (t == 255) carry = c + tmp[255];
        __syncthreads();
    }
    if (t == 255) offs[N_NODES] = carry;
}

__global__ __launch_bounds__(256) void edge_scatter(
    const int* __restrict__ src, const int* __restrict__ dst,
    const int* __restrict__ offs, int* __restrict__ fill,
    int* __restrict__ csr_src)
{
    for (int e = blockIdx.x * blockDim.x + threadIdx.x; e < N_EDGES;
         e += gridDim.x * blockDim.x) {
        const int d = dst[e];
        const int pos = offs[d] + atomicAdd(&fill[d], 1);
        csr_src[pos] = src[e];
    }
}

// ---------------------------------------------------------------------------
// Aggregation (gather, no atomics): one block per dst node; thread t owns
// output feature t (head = t>>5). Softmax shift is unnecessary: scores are
// bounded (|e| < ~3) so exp never overflows and softmax is shift-invariant.
// Denominator accumulates in-register (w identical across a head's 32 lanes).
// ELU fused; every output element written exactly once.
// ---------------------------------------------------------------------------
__global__ __launch_bounds__(128) void gat_aggregate(
    const int* __restrict__ offs,
    const int* __restrict__ csr_src,
    const float* __restrict__ h_all,
    const float* __restrict__ ssrc,
    const float* __restrict__ sdst,
    float* __restrict__ out)
{
    const int d = blockIdx.x;
    const int t = threadIdx.x;
    const int head = t >> 5;
    const int beg = offs[d], end = offs[d + 1];
    const float sd = sdst[d * NHEAD + head];

    float acc = 0.f, wsum = 0.f;
    __shared__ int sids[128];

    for (int base = beg; base < end; base += 128) {
        const int m = min(128, end - base);
        __syncthreads();
        if (t < m) sids[t] = csr_src[base + t];
        __syncthreads();

        int i = 0;
        for (; i + 4 <= m; i += 4) {
            const int s0 = sids[i], s1 = sids[i + 1];
            const int s2 = sids[i + 2], s3 = sids[i + 3];
            float e0 = ssrc[s0 * NHEAD + head] + sd;
            float e1 = ssrc[s1 * NHEAD + head] + sd;
            float e2 = ssrc[s2 * NHEAD + head] + sd;
            float e3 = ssrc[s3 * NHEAD + head] + sd;
            e0 = e0 > 0.f ? e0 : ALPHA * e0;
            e1 = e1 > 0.f ? e1 : ALPHA * e1;
            e2 = e2 > 0.f ? e2 : ALPHA * e2;
            e3 = e3 > 0.f ? e3 : ALPHA * e3;
            const float w0 = __expf(e0), w1 = __expf(e1);
            const float w2 = __expf(e2), w3 = __expf(e3);
            const float v0 = h_all[(size_t)s0 * HF + t];
            const float v1 = h_all[(size_t)s1 * HF + t];
            const float v2 = h_all[(size_t)s2 * HF + t];
            const float v3 = h_all[(size_t)s3 * HF + t];
            acc = fmaf(w0, v0, acc);
            acc = fmaf(w1, v1, acc);
            acc = fmaf(w2, v2, acc);
            acc = fmaf(w3, v3, acc);
            wsum += (w0 + w1) + (w2 + w3);
        }
        for (; i < m; ++i) {
            const int s = sids[i];
            float e = ssrc[s * NHEAD + head] + sd;
            e = e > 0.f ? e : ALPHA * e;
            const float w = __expf(e);
            acc = fmaf(w, h_all[(size_t)s * HF + t], acc);
            wsum += w;
        }
    }

    const float v = (wsum > 0.f) ? acc / wsum : 0.f;
    out[(size_t)d * HF + t] = v > 0.f ? v : expm1f(v);
}

// ---------------------------------------------------------------------------
extern "C" void kernel_launch(void* const* d_in, const int* in_sizes, int n_in,
                              void* d_out, int out_size, void* d_ws, size_t ws_size,
                              hipStream_t stream)
{
    const float* x     = (const float*)d_in[0];
    const int*   ei    = (const int*)d_in[1];   // [2][E]
    const float* W     = (const float*)d_in[2];
    const float* a_src = (const float*)d_in[3];
    const float* a_dst = (const float*)d_in[4];
    float* out = (float*)d_out;

    char* ws = (char*)d_ws;
    float* h_all   = (float*)(ws);                    // 25,600,000 B
    float* ssrc    = (float*)(ws + 25600000);         //    800,000 B
    float* sdst    = (float*)(ws + 26400000);         //    800,000 B
    int*   cnt     = (int*)  (ws + 27200000);         //    200,000 B
    int*   fill    = (int*)  (ws + 27400000);         //    200,000 B
    int*   offs    = (int*)  (ws + 27600000);         //    200,016 B
    int*   csr_src = (int*)  (ws + 27800016);         //  6,400,000 B  -> 34.2 MB

    const int* src = ei;
    const int* dst = ei + N_EDGES;

    hipMemsetAsync(cnt,  0, N_NODES * sizeof(int), stream);
    hipMemsetAsync(fill, 0, N_NODES * sizeof(int), stream);

    gat_gemm_scores<<<N_NODES, IN_FEAT, 0, stream>>>(
        x, W, a_src, a_dst, h_all, ssrc, sdst);

    edge_hist<<<2048, 256, 0, stream>>>(dst, cnt);
    scan_offsets<<<1, 256, 0, stream>>>(cnt, offs);
    edge_scatter<<<2048, 256, 0, stream>>>(src, dst, offs, fill, csr_src);

    gat_aggregate<<<N_NODES, HF, 0, stream>>>(
        offs, csr_src, h_all, ssrc, sdst, out);
}

// Round 4
// 480.681 us; speedup vs baseline: 3.3203x; 1.4202x over previous
//
#include <hip/hip_runtime.h>
#include <hip/hip_bf16.h>

#define N_NODES 50000
#define N_EDGES 1600000
#define IN_FEAT 128
#define OUT_FEAT 32
#define NHEAD 4
#define HF 128            // NHEAD * OUT_FEAT
#define ALPHA 0.2f

#define SCAN_CHUNK 512
#define NBLK_SCAN ((N_NODES + SCAN_CHUNK - 1) / SCAN_CHUNK)   // 98

// ---------------------------------------------------------------------------
// Kernel 1: h_all[n][h*32+f] = sum_k x[n][k] * W[h][k][f]
//           ssrc[n][h] = (h . a_src[h]) ; sdst likewise.
// One block (128 threads) per node.
// ---------------------------------------------------------------------------
__global__ __launch_bounds__(128) void gat_gemm_scores(
    const float* __restrict__ x,
    const float* __restrict__ W,       // [4][128][32]
    const float* __restrict__ a_src,   // [4][32]
    const float* __restrict__ a_dst,   // [4][32]
    float* __restrict__ h_all,         // [N][128]
    float* __restrict__ ssrc,          // [N][4]
    float* __restrict__ sdst)          // [N][4]
{
    const int n = blockIdx.x;
    const int t = threadIdx.x;     // 0..127
    const int head = t >> 5;
    const int f = t & 31;

    __shared__ float xrow[IN_FEAT];
    xrow[t] = x[(size_t)n * IN_FEAT + t];
    __syncthreads();

    const float* Wh = W + head * IN_FEAT * OUT_FEAT + f;
    float acc = 0.f;
#pragma unroll
    for (int k = 0; k < IN_FEAT; ++k)
        acc = fmaf(xrow[k], Wh[k * OUT_FEAT], acc);

    h_all[(size_t)n * HF + t] = acc;

    float vs = acc * a_src[head * OUT_FEAT + f];
    float vd = acc * a_dst[head * OUT_FEAT + f];
#pragma unroll
    for (int off = 16; off > 0; off >>= 1) {
        vs += __shfl_down(vs, off, 32);
        vd += __shfl_down(vd, off, 32);
    }
    if (f == 0) {
        ssrc[n * NHEAD + head] = vs;
        sdst[n * NHEAD + head] = vd;
    }
}

// ---------------------------------------------------------------------------
// CSR build: histogram of dst -> 3-level exclusive scan -> scatter src ids.
// ---------------------------------------------------------------------------
__global__ __launch_bounds__(256) void edge_hist(
    const int* __restrict__ dst, int* __restrict__ cnt)
{
    for (int e = blockIdx.x * blockDim.x + threadIdx.x; e < N_EDGES;
         e += gridDim.x * blockDim.x)
        atomicAdd(&cnt[dst[e]], 1);
}

// Level 1: each block scans SCAN_CHUNK elements (2 per thread), writes
// per-block exclusive prefixes into offs and the block total into bsum.
__global__ __launch_bounds__(256) void scan_blocks(
    const int* __restrict__ cnt, int* __restrict__ offs,
    int* __restrict__ bsum)
{
    __shared__ int tmp[256];
    const int t = threadIdx.x;
    const int base = blockIdx.x * SCAN_CHUNK;
    const int i0 = base + 2 * t, i1 = i0 + 1;
    const int c0 = (i0 < N_NODES) ? cnt[i0] : 0;
    const int c1 = (i1 < N_NODES) ? cnt[i1] : 0;
    const int v = c0 + c1;
    tmp[t] = v;
    __syncthreads();
#pragma unroll
    for (int off = 1; off < 256; off <<= 1) {
        const int add = (t >= off) ? tmp[t - off] : 0;
        __syncthreads();
        tmp[t] += add;
        __syncthreads();
    }
    const int ex = tmp[t] - v;   // exclusive prefix of this thread's pair
    if (i0 < N_NODES) offs[i0] = ex;
    if (i1 < N_NODES) offs[i1] = ex + c0;
    if (t == 255) bsum[blockIdx.x] = tmp[255];
}

// Level 2: one block scans the 98 block sums -> exclusive block prefixes.
__global__ __launch_bounds__(128) void scan_bsums(
    const int* __restrict__ bsum, int* __restrict__ bpre)
{
    __shared__ int tmp[128];
    const int t = threadIdx.x;
    const int v = (t < NBLK_SCAN) ? bsum[t] : 0;
    tmp[t] = v;
    __syncthreads();
#pragma unroll
    for (int off = 1; off < 128; off <<= 1) {
        const int add = (t >= off) ? tmp[t - off] : 0;
        __syncthreads();
        tmp[t] += add;
        __syncthreads();
    }
    if (t < NBLK_SCAN) bpre[t] = tmp[t] - v;
}

// Level 3: add block prefixes; total sentinel is the (constant) edge count.
__global__ __launch_bounds__(256) void scan_add(
    int* __restrict__ offs, const int* __restrict__ bpre)
{
    const int i = blockIdx.x * blockDim.x + threadIdx.x;
    if (i < N_NODES) offs[i] += bpre[i / SCAN_CHUNK];
    if (i == 0) offs[N_NODES] = N_EDGES;
}

__global__ __launch_bounds__(256) void edge_scatter(
    const int* __restrict__ src, const int* __restrict__ dst,
    const int* __restrict__ offs, int* __restrict__ fill,
    int* __restrict__ csr_src)
{
    for (int e = blockIdx.x * blockDim.x + threadIdx.x; e < N_EDGES;
         e += gridDim.x * blockDim.x) {
        const int d = dst[e];
        const int pos = offs[d] + atomicAdd(&fill[d], 1);
        csr_src[pos] = src[e];
    }
}

// ---------------------------------------------------------------------------
// Aggregation (gather, no atomics): one block per dst node; thread t owns
// output feature t (head = t>>5). Softmax shift is unnecessary: scores are
// bounded (|e| < ~3) so exp never overflows and softmax is shift-invariant.
// ELU fused; every output element written exactly once.
// ---------------------------------------------------------------------------
__global__ __launch_bounds__(128) void gat_aggregate(
    const int* __restrict__ offs,
    const int* __restrict__ csr_src,
    const float* __restrict__ h_all,
    const float* __restrict__ ssrc,
    const float* __restrict__ sdst,
    float* __restrict__ out)
{
    const int d = blockIdx.x;
    const int t = threadIdx.x;
    const int head = t >> 5;
    const int beg = offs[d], end = offs[d + 1];
    const float sd = sdst[d * NHEAD + head];

    float acc = 0.f, wsum = 0.f;
    __shared__ int sids[128];

    for (int base = beg; base < end; base += 128) {
        const int m = min(128, end - base);
        __syncthreads();
        if (t < m) sids[t] = csr_src[base + t];
        __syncthreads();

        int i = 0;
        for (; i + 4 <= m; i += 4) {
            const int s0 = sids[i], s1 = sids[i + 1];
            const int s2 = sids[i + 2], s3 = sids[i + 3];
            float e0 = ssrc[s0 * NHEAD + head] + sd;
            float e1 = ssrc[s1 * NHEAD + head] + sd;
            float e2 = ssrc[s2 * NHEAD + head] + sd;
            float e3 = ssrc[s3 * NHEAD + head] + sd;
            e0 = e0 > 0.f ? e0 : ALPHA * e0;
            e1 = e1 > 0.f ? e1 : ALPHA * e1;
            e2 = e2 > 0.f ? e2 : ALPHA * e2;
            e3 = e3 > 0.f ? e3 : ALPHA * e3;
            const float w0 = __expf(e0), w1 = __expf(e1);
            const float w2 = __expf(e2), w3 = __expf(e3);
            const float v0 = h_all[(size_t)s0 * HF + t];
            const float v1 = h_all[(size_t)s1 * HF + t];
            const float v2 = h_all[(size_t)s2 * HF + t];
            const float v3 = h_all[(size_t)s3 * HF + t];
            acc = fmaf(w0, v0, acc);
            acc = fmaf(w1, v1, acc);
            acc = fmaf(w2, v2, acc);
            acc = fmaf(w3, v3, acc);
            wsum += (w0 + w1) + (w2 + w3);
        }
        for (; i < m; ++i) {
            const int s = sids[i];
            float e = ssrc[s * NHEAD + head] + sd;
            e = e > 0.f ? e : ALPHA * e;
            const float w = __expf(e);
            acc = fmaf(w, h_all[(size_t)s * HF + t], acc);
            wsum += w;
        }
    }

    const float v = (wsum > 0.f) ? acc / wsum : 0.f;
    out[(size_t)d * HF + t] = v > 0.f ? v : expm1f(v);
}

// ---------------------------------------------------------------------------
extern "C" void kernel_launch(void* const* d_in, const int* in_sizes, int n_in,
                              void* d_out, int out_size, void* d_ws, size_t ws_size,
                              hipStream_t stream)
{
    const float* x     = (const float*)d_in[0];
    const int*   ei    = (const int*)d_in[1];   // [2][E]
    const float* W     = (const float*)d_in[2];
    const float* a_src = (const float*)d_in[3];
    const float* a_dst = (const float*)d_in[4];
    float* out = (float*)d_out;

    char* ws = (char*)d_ws;
    float* h_all   = (float*)(ws);                    // 25,600,000 B
    float* ssrc    = (float*)(ws + 25600000);         //    800,000 B
    float* sdst    = (float*)(ws + 26400000);         //    800,000 B
    int*   cnt     = (int*)  (ws + 27200000);         //    200,000 B
    int*   fill    = (int*)  (ws + 27400000);         //    200,000 B
    int*   offs    = (int*)  (ws + 27600000);         //    200,016 B
    int*   bsum    = (int*)  (ws + 27800064);         //        392 B
    int*   bpre    = (int*)  (ws + 27800576);         //        392 B
    int*   csr_src = (int*)  (ws + 27801088);         //  6,400,000 B

    const int* src = ei;
    const int* dst = ei + N_EDGES;

    hipMemsetAsync(cnt,  0, N_NODES * sizeof(int), stream);
    hipMemsetAsync(fill, 0, N_NODES * sizeof(int), stream);

    gat_gemm_scores<<<N_NODES, IN_FEAT, 0, stream>>>(
        x, W, a_src, a_dst, h_all, ssrc, sdst);

    edge_hist<<<2048, 256, 0, stream>>>(dst, cnt);
    scan_blocks<<<NBLK_SCAN, 256, 0, stream>>>(cnt, offs, bsum);
    scan_bsums<<<1, 128, 0, stream>>>(bsum, bpre);
    scan_add<<<(N_NODES + 255) / 256, 256, 0, stream>>>(offs, bpre);
    edge_scatter<<<2048, 256, 0, stream>>>(src, dst, offs, fill, csr_src);

    gat_aggregate<<<N_NODES, HF, 0, stream>>>(
        offs, csr_src, h_all, ssrc, sdst, out);
}

// Round 7
// 404.901 us; speedup vs baseline: 3.9417x; 1.1872x over previous
//
#include <hip/hip_runtime.h>
#include <hip/hip_bf16.h>

#define N_NODES 50000
#define N_EDGES 1600000
#define IN_FEAT 128
#define OUT_FEAT 32
#define NHEAD 4
#define HF 128            // NHEAD * OUT_FEAT
#define ALPHA 0.2f

#define M_BLK 32
#define NBLK_GEMM ((N_NODES + M_BLK - 1) / M_BLK)            // 1563

#define SCAN_CHUNK 512
#define NBLK_SCAN ((N_NODES + SCAN_CHUNK - 1) / SCAN_CHUNK)  // 98

// ---------------------------------------------------------------------------
// Prep (tiny): Wt[c][k] = W[c>>5][k][c&31]  (transpose so per-output-column
// weight reads are contiguous), and score projection vectors
// p_src[h][k] = sum_f W[h][k][f]*a_src[h][f] (likewise p_dst), which lets the
// GEMM kernel produce attention scores as dot(x_row, p) — no reductions.
// ---------------------------------------------------------------------------
__global__ __launch_bounds__(256) void gat_prep(
    const float* __restrict__ W, const float* __restrict__ a_src,
    const float* __restrict__ a_dst, float* __restrict__ Wt,
    float* __restrict__ p_src, float* __restrict__ p_dst)
{
    const int t = threadIdx.x;
    if (blockIdx.x == 0) {
        for (int idx = t; idx < 16384; idx += 256) {
            const int c = idx & 127, k = idx >> 7;
            Wt[c * 128 + k] = W[(c >> 5) * 4096 + k * 32 + (c & 31)];
        }
    } else {
        for (int idx = t; idx < 1024; idx += 256) {
            const int which = idx >> 9, h = (idx >> 7) & 3, k = idx & 127;
            const float* a = (which ? a_dst : a_src) + h * 32;
            const float* wrow = W + h * 4096 + k * 32;
            float s = 0.f;
#pragma unroll
            for (int f = 0; f < 32; ++f) s = fmaf(wrow[f], a[f], s);
            (which ? p_dst : p_src)[h * 128 + k] = s;
        }
    }
}

// ---------------------------------------------------------------------------
// Register-tiled GEMM + fused scores. Block = 256 thr, tile = 32 nodes.
// Thread t: col c = t&127, rows rbase..rbase+15 (rbase = (t>>7)*16).
// x tile staged in LDS (reads are wave-uniform -> broadcast, conflict-free);
// Wt streamed as float4 (L1/L2-hot, 64 KB shared by all blocks).
// h written as bf16 (halves the aggregate gather traffic).
// ---------------------------------------------------------------------------
__global__ __launch_bounds__(256) void gat_gemm_scores(
    const float* __restrict__ x, const float* __restrict__ Wt,
    const float* __restrict__ p_src, const float* __restrict__ p_dst,
    __hip_bfloat16* __restrict__ h_bf,
    float* __restrict__ ssrc, float* __restrict__ sdst)
{
    const int nb = blockIdx.x;
    const int t = threadIdx.x;
    const int row0 = nb * M_BLK;

    __shared__ float xs[M_BLK][IN_FEAT + 4];   // +4 pad: score-phase conflicts

    {   // stage x tile (coalesced float4)
        const float4* x4 = (const float4*)x;
        for (int j = 0; j < 4; ++j) {
            const int fi = t + j * 256;            // 0..1023 float4 slots
            const int r = fi >> 5, c4 = fi & 31;
            float4 v = make_float4(0.f, 0.f, 0.f, 0.f);
            if (row0 + r < N_NODES) v = x4[(size_t)(row0 + r) * 32 + c4];
            xs[r][c4 * 4 + 0] = v.x; xs[r][c4 * 4 + 1] = v.y;
            xs[r][c4 * 4 + 2] = v.z; xs[r][c4 * 4 + 3] = v.w;
        }
    }
    __syncthreads();

    const int c = t & 127;
    const int rbase = (t >> 7) * 16;

    float acc[16];
#pragma unroll
    for (int r = 0; r < 16; ++r) acc[r] = 0.f;

    const float4* wc = (const float4*)(Wt + c * 128);
#pragma unroll 4
    for (int kk = 0; kk < 32; ++kk) {
        const float4 wv = wc[kk];
#pragma unroll
        for (int r = 0; r < 16; ++r) {
            const float4 xv = *(const float4*)&xs[rbase + r][kk * 4];
            acc[r] = fmaf(xv.x, wv.x, acc[r]);
            acc[r] = fmaf(xv.y, wv.y, acc[r]);
            acc[r] = fmaf(xv.z, wv.z, acc[r]);
            acc[r] = fmaf(xv.w, wv.w, acc[r]);
        }
    }

#pragma unroll
    for (int r = 0; r < 16; ++r) {
        const int row = row0 + rbase + r;
        if (row < N_NODES)
            h_bf[(size_t)row * HF + c] = __float2bfloat16(acc[r]);
    }

    {   // scores: thread -> (row = t&31, head, src/dst)
        const int r = t & 31;
        const int head = (t >> 5) & 3;
        const int which = t >> 7;
        const float4* pv4 = (const float4*)((which ? p_dst : p_src) + head * 128);
        float s = 0.f;
#pragma unroll 8
        for (int k4 = 0; k4 < 32; ++k4) {
            const float4 xv = *(const float4*)&xs[r][k4 * 4];
            const float4 p4 = pv4[k4];
            s = fmaf(xv.x, p4.x, s); s = fmaf(xv.y, p4.y, s);
            s = fmaf(xv.z, p4.z, s); s = fmaf(xv.w, p4.w, s);
        }
        const int row = row0 + r;
        if (row < N_NODES) {
            if (which == 0) ssrc[row * NHEAD + head] = s;
            else            sdst[row * NHEAD + head] = s;
        }
    }
}

// ---------------------------------------------------------------------------
// CSR build: histogram of dst -> 3-level exclusive scan -> scatter src ids.
// ---------------------------------------------------------------------------
__global__ __launch_bounds__(256) void edge_hist(
    const int* __restrict__ dst, int* __restrict__ cnt)
{
    for (int e = blockIdx.x * blockDim.x + threadIdx.x; e < N_EDGES;
         e += gridDim.x * blockDim.x)
        atomicAdd(&cnt[dst[e]], 1);
}

__global__ __launch_bounds__(256) void scan_blocks(
    const int* __restrict__ cnt, int* __restrict__ offs,
    int* __restrict__ bsum)
{
    __shared__ int tmp[256];
    const int t = threadIdx.x;
    const int base = blockIdx.x * SCAN_CHUNK;
    const int i0 = base + 2 * t, i1 = i0 + 1;
    const int c0 = (i0 < N_NODES) ? cnt[i0] : 0;
    const int c1 = (i1 < N_NODES) ? cnt[i1] : 0;
    const int v = c0 + c1;
    tmp[t] = v;
    __syncthreads();
#pragma unroll
    for (int off = 1; off < 256; off <<= 1) {
        const int add = (t >= off) ? tmp[t - off] : 0;
        __syncthreads();
        tmp[t] += add;
        __syncthreads();
    }
    const int ex = tmp[t] - v;
    if (i0 < N_NODES) offs[i0] = ex;
    if (i1 < N_NODES) offs[i1] = ex + c0;
    if (t == 255) bsum[blockIdx.x] = tmp[255];
}

__global__ __launch_bounds__(128) void scan_bsums(
    const int* __restrict__ bsum, int* __restrict__ bpre)
{
    __shared__ int tmp[128];
    const int t = threadIdx.x;
    const int v = (t < NBLK_SCAN) ? bsum[t] : 0;
    tmp[t] = v;
    __syncthreads();
#pragma unroll
    for (int off = 1; off < 128; off <<= 1) {
        const int add = (t >= off) ? tmp[t - off] : 0;
        __syncthreads();
        tmp[t] += add;
        __syncthreads();
    }
    if (t < NBLK_SCAN) bpre[t] = tmp[t] - v;
}

// adds block prefixes AND initializes fill = offs (scatter uses fill alone).
__global__ __launch_bounds__(256) void scan_add(
    int* __restrict__ offs, const int* __restrict__ bpre,
    int* __restrict__ fill)
{
    const int i = blockIdx.x * blockDim.x + threadIdx.x;
    if (i < N_NODES) {
        const int v = offs[i] + bpre[i / SCAN_CHUNK];
        offs[i] = v;
        fill[i] = v;
    }
    if (i == 0) offs[N_NODES] = N_EDGES;
}

__global__ __launch_bounds__(256) void edge_scatter(
    const int* __restrict__ src, const int* __restrict__ dst,
    int* __restrict__ fill, int* __restrict__ csr_src)
{
    for (int e = blockIdx.x * blockDim.x + threadIdx.x; e < N_EDGES;
         e += gridDim.x * blockDim.x) {
        const int pos = atomicAdd(&fill[dst[e]], 1);
        csr_src[pos] = src[e];
    }
}

// ---------------------------------------------------------------------------
// Aggregation (gather, no atomics): one block per dst node; thread t owns
// output feature t (head = t>>5). Per 128-edge chunk, edge weights are
// computed ONCE (4 exps/edge, by the staging thread) into LDS instead of
// redundantly per feature lane (was 128 exps/edge). Softmax shift is
// unnecessary: |e| bounded ~3, exp can't overflow, softmax shift-invariant.
// ---------------------------------------------------------------------------
__global__ __launch_bounds__(128) void gat_aggregate(
    const int* __restrict__ offs,
    const int* __restrict__ csr_src,
    const __hip_bfloat16* __restrict__ h_bf,
    const float4* __restrict__ ssrc4,
    const float4* __restrict__ sdst4,
    float* __restrict__ out)
{
    const int d = blockIdx.x;
    const int t = threadIdx.x;
    const int head = t >> 5;
    const int beg = offs[d], end = offs[d + 1];
    const float4 sd = sdst4[d];

    __shared__ int sids[128];
    __shared__ float wls[128 * 4];

    float acc = 0.f, wsum = 0.f;

    for (int base = beg; base < end; base += 128) {
        const int m = min(128, end - base);
        __syncthreads();
        if (t < m) {
            const int s = csr_src[base + t];
            sids[t] = s;
            const float4 ss = ssrc4[s];
            float e0 = ss.x + sd.x, e1 = ss.y + sd.y;
            float e2 = ss.z + sd.z, e3 = ss.w + sd.w;
            e0 = e0 > 0.f ? e0 : ALPHA * e0;
            e1 = e1 > 0.f ? e1 : ALPHA * e1;
            e2 = e2 > 0.f ? e2 : ALPHA * e2;
            e3 = e3 > 0.f ? e3 : ALPHA * e3;
            wls[t * 4 + 0] = __expf(e0);
            wls[t * 4 + 1] = __expf(e1);
            wls[t * 4 + 2] = __expf(e2);
            wls[t * 4 + 3] = __expf(e3);
        }
        __syncthreads();

        int i = 0;
        for (; i + 4 <= m; i += 4) {
            const int s0 = sids[i], s1 = sids[i + 1];
            const int s2 = sids[i + 2], s3 = sids[i + 3];
            const float w0 = wls[(i + 0) * 4 + head];
            const float w1 = wls[(i + 1) * 4 + head];
            const float w2 = wls[(i + 2) * 4 + head];
            const float w3 = wls[(i + 3) * 4 + head];
            const float v0 = __bfloat162float(h_bf[(size_t)s0 * HF + t]);
            const float v1 = __bfloat162float(h_bf[(size_t)s1 * HF + t]);
            const float v2 = __bfloat162float(h_bf[(size_t)s2 * HF + t]);
            const float v3 = __bfloat162float(h_bf[(size_t)s3 * HF + t]);
            acc = fmaf(w0, v0, acc); acc = fmaf(w1, v1, acc);
            acc = fmaf(w2, v2, acc); acc = fmaf(w3, v3, acc);
            wsum += (w0 + w1) + (w2 + w3);
        }
        for (; i < m; ++i) {
            const float w = wls[i * 4 + head];
            acc = fmaf(w, __bfloat162float(h_bf[(size_t)sids[i] * HF + t]), acc);
            wsum += w;
        }
    }

    const float v = (wsum > 0.f) ? acc / wsum : 0.f;
    out[(size_t)d * HF + t] = v > 0.f ? v : expm1f(v);
}

// ---------------------------------------------------------------------------
extern "C" void kernel_launch(void* const* d_in, const int* in_sizes, int n_in,
                              void* d_out, int out_size, void* d_ws, size_t ws_size,
                              hipStream_t stream)
{
    const float* x     = (const float*)d_in[0];
    const int*   ei    = (const int*)d_in[1];   // [2][E]
    const float* W     = (const float*)d_in[2];
    const float* a_src = (const float*)d_in[3];
    const float* a_dst = (const float*)d_in[4];
    float* out = (float*)d_out;

    char* ws = (char*)d_ws;
    __hip_bfloat16* h_bf = (__hip_bfloat16*)(ws);     // 12,800,000 B
    float* ssrc    = (float*)(ws + 12800000);         //    800,000 B
    float* sdst    = (float*)(ws + 13600000);         //    800,000 B
    int*   cnt     = (int*)  (ws + 14400000);         //    200,000 B
    int*   fill    = (int*)  (ws + 14600000);         //    200,000 B
    int*   offs    = (int*)  (ws + 14800000);         //    200,016 B
    int*   bsum    = (int*)  (ws + 15000016);         //        392 B
    int*   bpre    = (int*)  (ws + 15000416);         //        392 B
    float* Wt      = (float*)(ws + 15000816);         //     65,536 B
    float* p_src   = (float*)(ws + 15066352);         //      2,048 B
    float* p_dst   = (float*)(ws + 15068400);         //      2,048 B
    int*   csr_src = (int*)  (ws + 15070448);         //  6,400,000 B

    const int* src = ei;
    const int* dst = ei + N_EDGES;

    hipMemsetAsync(cnt, 0, N_NODES * sizeof(int), stream);

    gat_prep<<<2, 256, 0, stream>>>(W, a_src, a_dst, Wt, p_src, p_dst);

    gat_gemm_scores<<<NBLK_GEMM, 256, 0, stream>>>(
        x, Wt, p_src, p_dst, h_bf, ssrc, sdst);

    edge_hist<<<2048, 256, 0, stream>>>(dst, cnt);
    scan_blocks<<<NBLK_SCAN, 256, 0, stream>>>(cnt, offs, bsum);
    scan_bsums<<<1, 128, 0, stream>>>(bsum, bpre);
    scan_add<<<(N_NODES + 255) / 256, 256, 0, stream>>>(offs, bpre, fill);
    edge_scatter<<<2048, 256, 0, stream>>>(src, dst, fill, csr_src);

    gat_aggregate<<<N_NODES, HF, 0, stream>>>(
        offs, csr_src, h_bf, (const float4*)ssrc, (const float4*)sdst, out);
}

// Round 14
// 271.049 us; speedup vs baseline: 5.8882x; 1.4938x over previous
//
#include <hip/hip_runtime.h>
#include <hip/hip_bf16.h>

#define N_NODES 50000
#define N_EDGES 1600000
#define IN_FEAT 128
#define OUT_FEAT 32
#define NHEAD 4
#define HF 128            // NHEAD * OUT_FEAT
#define ALPHA 0.2f

#define M_BLK 32
#define NBLK_GEMM ((N_NODES + M_BLK - 1) / M_BLK)            // 1563

#define NB 196            // dst buckets (dst>>8), 50000/256 -> 196
#define BCAP 9216         // slots per bucket (mean 8192, +11 sigma)
#define CHUNK 4096
#define NCHUNK ((N_EDGES + CHUNK - 1) / CHUNK)               // 391

// ---------------------------------------------------------------------------
// Prep (tiny): Wt[c][k] = W[c>>5][k][c&31]  (transpose so per-output-column
// weight reads are contiguous), and score projection vectors
// p_src[h][k] = sum_f W[h][k][f]*a_src[h][f] (likewise p_dst): scores become
// dot(x_row, p) — no per-head reductions in the GEMM kernel.
// ---------------------------------------------------------------------------
__global__ __launch_bounds__(256) void gat_prep(
    const float* __restrict__ W, const float* __restrict__ a_src,
    const float* __restrict__ a_dst, float* __restrict__ Wt,
    float* __restrict__ p_src, float* __restrict__ p_dst)
{
    const int t = threadIdx.x;
    if (blockIdx.x == 0) {
        for (int idx = t; idx < 16384; idx += 256) {
            const int c = idx & 127, k = idx >> 7;
            Wt[c * 128 + k] = W[(c >> 5) * 4096 + k * 32 + (c & 31)];
        }
    } else {
        for (int idx = t; idx < 1024; idx += 256) {
            const int which = idx >> 9, h = (idx >> 7) & 3, k = idx & 127;
            const float* a = (which ? a_dst : a_src) + h * 32;
            const float* wrow = W + h * 4096 + k * 32;
            float s = 0.f;
#pragma unroll
            for (int f = 0; f < 32; ++f) s = fmaf(wrow[f], a[f], s);
            (which ? p_dst : p_src)[h * 128 + k] = s;
        }
    }
}

// ---------------------------------------------------------------------------
// Register-tiled GEMM + fused scores. Block = 256 thr, tile = 32 nodes.
// Thread t: col c = t&127, rows rbase..rbase+15. x tile in LDS (broadcast
// reads); Wt streamed as float4 (L2-hot). h written as bf16.
// ---------------------------------------------------------------------------
__global__ __launch_bounds__(256) void gat_gemm_scores(
    const float* __restrict__ x, const float* __restrict__ Wt,
    const float* __restrict__ p_src, const float* __restrict__ p_dst,
    __hip_bfloat16* __restrict__ h_bf,
    float* __restrict__ ssrc, float* __restrict__ sdst)
{
    const int nb = blockIdx.x;
    const int t = threadIdx.x;
    const int row0 = nb * M_BLK;

    __shared__ float xs[M_BLK][IN_FEAT + 4];

    {   // stage x tile (coalesced float4)
        const float4* x4 = (const float4*)x;
        for (int j = 0; j < 4; ++j) {
            const int fi = t + j * 256;
            const int r = fi >> 5, c4 = fi & 31;
            float4 v = make_float4(0.f, 0.f, 0.f, 0.f);
            if (row0 + r < N_NODES) v = x4[(size_t)(row0 + r) * 32 + c4];
            xs[r][c4 * 4 + 0] = v.x; xs[r][c4 * 4 + 1] = v.y;
            xs[r][c4 * 4 + 2] = v.z; xs[r][c4 * 4 + 3] = v.w;
        }
    }
    __syncthreads();

    const int c = t & 127;
    const int rbase = (t >> 7) * 16;

    float acc[16];
#pragma unroll
    for (int r = 0; r < 16; ++r) acc[r] = 0.f;

    const float4* wc = (const float4*)(Wt + c * 128);
#pragma unroll 4
    for (int kk = 0; kk < 32; ++kk) {
        const float4 wv = wc[kk];
#pragma unroll
        for (int r = 0; r < 16; ++r) {
            const float4 xv = *(const float4*)&xs[rbase + r][kk * 4];
            acc[r] = fmaf(xv.x, wv.x, acc[r]);
            acc[r] = fmaf(xv.y, wv.y, acc[r]);
            acc[r] = fmaf(xv.z, wv.z, acc[r]);
            acc[r] = fmaf(xv.w, wv.w, acc[r]);
        }
    }

#pragma unroll
    for (int r = 0; r < 16; ++r) {
        const int row = row0 + rbase + r;
        if (row < N_NODES)
            h_bf[(size_t)row * HF + c] = __float2bfloat16(acc[r]);
    }

    {   // scores: thread -> (row = t&31, head, src/dst)
        const int r = t & 31;
        const int head = (t >> 5) & 3;
        const int which = t >> 7;
        const float4* pv4 = (const float4*)((which ? p_dst : p_src) + head * 128);
        float s = 0.f;
#pragma unroll 8
        for (int k4 = 0; k4 < 32; ++k4) {
            const float4 xv = *(const float4*)&xs[r][k4 * 4];
            const float4 p4 = pv4[k4];
            s = fmaf(xv.x, p4.x, s); s = fmaf(xv.y, p4.y, s);
            s = fmaf(xv.z, p4.z, s); s = fmaf(xv.w, p4.w, s);
        }
        const int row = row0 + r;
        if (row < N_NODES) {
            if (which == 0) ssrc[row * NHEAD + head] = s;
            else            sdst[row * NHEAD + head] = s;
        }
    }
}

// ---------------------------------------------------------------------------
// CSR build, pass 1: block-reserved bucket binning. Each block handles a
// 4096-edge chunk: LDS histogram over 196 buckets (dst>>8), ONE global
// atomic per (block,bucket) to reserve a contiguous run, then writes packed
// (dlocal<<16 | src) words into its own run -> L2 write-combining works.
// ---------------------------------------------------------------------------
__global__ __launch_bounds__(256) void bucket_bin(
    const int* __restrict__ src, const int* __restrict__ dst,
    int* __restrict__ cursor, unsigned int* __restrict__ buf)
{
    __shared__ int hist[NB], base[NB], fill[NB];
    const int t = threadIdx.x;
    const int e0 = blockIdx.x * CHUNK;
    const int n = min(CHUNK, N_EDGES - e0);

    for (int b = t; b < NB; b += 256) { hist[b] = 0; fill[b] = 0; }
    __syncthreads();

    for (int i = t; i < n; i += 256)
        atomicAdd(&hist[dst[e0 + i] >> 8], 1);
    __syncthreads();

    for (int b = t; b < NB; b += 256)
        base[b] = hist[b] ? atomicAdd(&cursor[b], hist[b]) : 0;
    __syncthreads();

    for (int i = t; i < n; i += 256) {
        const int d = dst[e0 + i];
        const int b = d >> 8;
        const int slot = base[b] + atomicAdd(&fill[b], 1);
        buf[b * BCAP + slot] = (unsigned)src[e0 + i] | ((unsigned)(d & 255) << 16);
    }
}

// ---------------------------------------------------------------------------
// CSR build, pass 2a: exclusive scan of the 196 bucket counts -> bases.
// ---------------------------------------------------------------------------
__global__ __launch_bounds__(256) void bucket_scan(
    const int* __restrict__ cursor, int* __restrict__ bbase,
    int* __restrict__ offs)
{
    __shared__ int tmp[256];
    const int t = threadIdx.x;
    const int v = (t < NB) ? cursor[t] : 0;
    tmp[t] = v;
    __syncthreads();
#pragma unroll
    for (int off = 1; off < 256; off <<= 1) {
        const int a = (t >= off) ? tmp[t - off] : 0;
        __syncthreads();
        tmp[t] += a;
        __syncthreads();
    }
    if (t < NB) bbase[t] = tmp[t] - v;
    if (t == 0) offs[N_NODES] = N_EDGES;
}

// ---------------------------------------------------------------------------
// CSR build, pass 2b: one block per bucket. LDS histogram over the 256
// bucket-local dsts, LDS scan -> offs[] (global CSR offsets), then scatter
// src ids into the block's contiguous csr region (LDS fill counters only).
// ---------------------------------------------------------------------------
__global__ __launch_bounds__(256) void csr_build(
    const unsigned int* __restrict__ buf, const int* __restrict__ cursor,
    const int* __restrict__ bbase, int* __restrict__ offs,
    int* __restrict__ csr_src)
{
    __shared__ int h2[256], loc[256], tmp[256];
    const int b = blockIdx.x;
    const int t = threadIdx.x;
    const int cnt = cursor[b];
    const int base = bbase[b];
    const unsigned int* bb = buf + b * BCAP;

    h2[t] = 0;
    __syncthreads();
    for (int i = t; i < cnt; i += 256)
        atomicAdd(&h2[bb[i] >> 16], 1);
    __syncthreads();

    tmp[t] = h2[t];
    __syncthreads();
#pragma unroll
    for (int off = 1; off < 256; off <<= 1) {
        const int a = (t >= off) ? tmp[t - off] : 0;
        __syncthreads();
        tmp[t] += a;
        __syncthreads();
    }
    loc[t] = tmp[t] - h2[t];
    __syncthreads();

    const int d = (b << 8) + t;
    if (d < N_NODES) offs[d] = base + loc[t];

    h2[t] = loc[t];          // reuse as fill counters
    __syncthreads();

    for (int i = t; i < cnt; i += 256) {
        const unsigned int p = bb[i];
        const int pos = base + atomicAdd(&h2[p >> 16], 1);
        csr_src[pos] = (int)(p & 0xFFFFu);
    }
}

// ---------------------------------------------------------------------------
// Aggregation (gather, no atomics): one block per dst node; thread t owns
// output feature t (head = t>>5). Edge weights computed once per edge (4
// exps) into LDS. No segment-max needed: |e| bounded ~3, softmax is
// shift-invariant. ELU fused; each output element written exactly once.
// ---------------------------------------------------------------------------
__global__ __launch_bounds__(128) void gat_aggregate(
    const int* __restrict__ offs,
    const int* __restrict__ csr_src,
    const __hip_bfloat16* __restrict__ h_bf,
    const float4* __restrict__ ssrc4,
    const float4* __restrict__ sdst4,
    float* __restrict__ out)
{
    const int d = blockIdx.x;
    const int t = threadIdx.x;
    const int head = t >> 5;
    const int beg = offs[d], end = offs[d + 1];
    const float4 sd = sdst4[d];

    __shared__ int sids[128];
    __shared__ float wls[128 * 4];

    float acc = 0.f, wsum = 0.f;

    for (int base = beg; base < end; base += 128) {
        const int m = min(128, end - base);
        __syncthreads();
        if (t < m) {
            const int s = csr_src[base + t];
            sids[t] = s;
            const float4 ss = ssrc4[s];
            float e0 = ss.x + sd.x, e1 = ss.y + sd.y;
            float e2 = ss.z + sd.z, e3 = ss.w + sd.w;
            e0 = e0 > 0.f ? e0 : ALPHA * e0;
            e1 = e1 > 0.f ? e1 : ALPHA * e1;
            e2 = e2 > 0.f ? e2 : ALPHA * e2;
            e3 = e3 > 0.f ? e3 : ALPHA * e3;
            wls[t * 4 + 0] = __expf(e0);
            wls[t * 4 + 1] = __expf(e1);
            wls[t * 4 + 2] = __expf(e2);
            wls[t * 4 + 3] = __expf(e3);
        }
        __syncthreads();

        int i = 0;
        for (; i + 4 <= m; i += 4) {
            const int s0 = sids[i], s1 = sids[i + 1];
            const int s2 = sids[i + 2], s3 = sids[i + 3];
            const float w0 = wls[(i + 0) * 4 + head];
            const float w1 = wls[(i + 1) * 4 + head];
            const float w2 = wls[(i + 2) * 4 + head];
            const float w3 = wls[(i + 3) * 4 + head];
            const float v0 = __bfloat162float(h_bf[(size_t)s0 * HF + t]);
            const float v1 = __bfloat162float(h_bf[(size_t)s1 * HF + t]);
            const float v2 = __bfloat162float(h_bf[(size_t)s2 * HF + t]);
            const float v3 = __bfloat162float(h_bf[(size_t)s3 * HF + t]);
            acc = fmaf(w0, v0, acc); acc = fmaf(w1, v1, acc);
            acc = fmaf(w2, v2, acc); acc = fmaf(w3, v3, acc);
            wsum += (w0 + w1) + (w2 + w3);
        }
        for (; i < m; ++i) {
            const float w = wls[i * 4 + head];
            acc = fmaf(w, __bfloat162float(h_bf[(size_t)sids[i] * HF + t]), acc);
            wsum += w;
        }
    }

    const float v = (wsum > 0.f) ? acc / wsum : 0.f;
    out[(size_t)d * HF + t] = v > 0.f ? v : expm1f(v);
}

// ---------------------------------------------------------------------------
extern "C" void kernel_launch(void* const* d_in, const int* in_sizes, int n_in,
                              void* d_out, int out_size, void* d_ws, size_t ws_size,
                              hipStream_t stream)
{
    const float* x     = (const float*)d_in[0];
    const int*   ei    = (const int*)d_in[1];   // [2][E]
    const float* W     = (const float*)d_in[2];
    const float* a_src = (const float*)d_in[3];
    const float* a_dst = (const float*)d_in[4];
    float* out = (float*)d_out;

    char* ws = (char*)d_ws;
    __hip_bfloat16* h_bf = (__hip_bfloat16*)(ws);     // 12,800,000 B
    float* ssrc    = (float*)(ws + 12800000);         //    800,000 B
    float* sdst    = (float*)(ws + 13600000);         //    800,000 B
    int*   offs    = (int*)  (ws + 14400000);         //    200,016 B
    float* Wt      = (float*)(ws + 14600016);         //     65,536 B
    float* p_src   = (float*)(ws + 14665552);         //      2,048 B
    float* p_dst   = (float*)(ws + 14667600);         //      2,048 B
    int*   cursor  = (int*)  (ws + 14669648);         //        784 B
    int*   bbase   = (int*)  (ws + 14670432);         //        784 B
    unsigned int* bbuf = (unsigned int*)(ws + 14671216); // 7,225,344 B
    int*   csr_src = (int*)  (ws + 21896560);         //  6,400,000 B -> 28.3 MB

    const int* src = ei;
    const int* dst = ei + N_EDGES;

    hipMemsetAsync(cursor, 0, NB * sizeof(int), stream);

    gat_prep<<<2, 256, 0, stream>>>(W, a_src, a_dst, Wt, p_src, p_dst);

    gat_gemm_scores<<<NBLK_GEMM, 256, 0, stream>>>(
        x, Wt, p_src, p_dst, h_bf, ssrc, sdst);

    bucket_bin<<<NCHUNK, 256, 0, stream>>>(src, dst, cursor, bbuf);
    bucket_scan<<<1, 256, 0, stream>>>(cursor, bbase, offs);
    csr_build<<<NB, 256, 0, stream>>>(bbuf, cursor, bbase, offs, csr_src);

    gat_aggregate<<<N_NODES, HF, 0, stream>>>(
        offs, csr_src, h_bf, (const float4*)ssrc, (const float4*)sdst, out);
}

// Round 16
// 268.376 us; speedup vs baseline: 5.9468x; 1.0100x over previous
//
#include <hip/hip_runtime.h>
#include <hip/hip_bf16.h>

#define N_NODES 50000
#define N_EDGES 1600000
#define IN_FEAT 128
#define OUT_FEAT 32
#define NHEAD 4
#define HF 128            // NHEAD * OUT_FEAT
#define ALPHA 0.2f

#define M_BLK 32
#define NBLK_GEMM ((N_NODES + M_BLK - 1) / M_BLK)            // 1563

#define NB 196            // dst buckets (dst>>8), 50000/256 -> 196
#define BCAP 9216         // slots per bucket (mean 8192, +11 sigma)
#define CHUNK 4096
#define NCHUNK ((N_EDGES + CHUNK - 1) / CHUNK)               // 391

// ---------------------------------------------------------------------------
// Prep (tiny): Wt[c][k] = W[c>>5][k][c&31]  (transpose so per-output-column
// weight reads are contiguous), and score projection vectors
// p_src[h][k] = sum_f W[h][k][f]*a_src[h][f] (likewise p_dst): scores become
// dot(x_row, p) — no per-head reductions in the GEMM kernel.
// ---------------------------------------------------------------------------
__global__ __launch_bounds__(256) void gat_prep(
    const float* __restrict__ W, const float* __restrict__ a_src,
    const float* __restrict__ a_dst, float* __restrict__ Wt,
    float* __restrict__ p_src, float* __restrict__ p_dst)
{
    const int t = threadIdx.x;
    if (blockIdx.x == 0) {
        for (int idx = t; idx < 16384; idx += 256) {
            const int c = idx & 127, k = idx >> 7;
            Wt[c * 128 + k] = W[(c >> 5) * 4096 + k * 32 + (c & 31)];
        }
    } else {
        for (int idx = t; idx < 1024; idx += 256) {
            const int which = idx >> 9, h = (idx >> 7) & 3, k = idx & 127;
            const float* a = (which ? a_dst : a_src) + h * 32;
            const float* wrow = W + h * 4096 + k * 32;
            float s = 0.f;
#pragma unroll
            for (int f = 0; f < 32; ++f) s = fmaf(wrow[f], a[f], s);
            (which ? p_dst : p_src)[h * 128 + k] = s;
        }
    }
}

// ---------------------------------------------------------------------------
// Register-tiled GEMM + fused scores. Block = 256 thr, tile = 32 nodes.
// Thread t: col c = t&127, rows rbase..rbase+15. x tile in LDS (broadcast
// reads); Wt streamed as float4 (L2-hot). h written as bf16.
// ---------------------------------------------------------------------------
__global__ __launch_bounds__(256) void gat_gemm_scores(
    const float* __restrict__ x, const float* __restrict__ Wt,
    const float* __restrict__ p_src, const float* __restrict__ p_dst,
    __hip_bfloat16* __restrict__ h_bf,
    float* __restrict__ ssrc, float* __restrict__ sdst)
{
    const int nb = blockIdx.x;
    const int t = threadIdx.x;
    const int row0 = nb * M_BLK;

    __shared__ float xs[M_BLK][IN_FEAT + 4];

    {   // stage x tile (coalesced float4)
        const float4* x4 = (const float4*)x;
        for (int j = 0; j < 4; ++j) {
            const int fi = t + j * 256;
            const int r = fi >> 5, c4 = fi & 31;
            float4 v = make_float4(0.f, 0.f, 0.f, 0.f);
            if (row0 + r < N_NODES) v = x4[(size_t)(row0 + r) * 32 + c4];
            xs[r][c4 * 4 + 0] = v.x; xs[r][c4 * 4 + 1] = v.y;
            xs[r][c4 * 4 + 2] = v.z; xs[r][c4 * 4 + 3] = v.w;
        }
    }
    __syncthreads();

    const int c = t & 127;
    const int rbase = (t >> 7) * 16;

    float acc[16];
#pragma unroll
    for (int r = 0; r < 16; ++r) acc[r] = 0.f;

    const float4* wc = (const float4*)(Wt + c * 128);
#pragma unroll 4
    for (int kk = 0; kk < 32; ++kk) {
        const float4 wv = wc[kk];
#pragma unroll
        for (int r = 0; r < 16; ++r) {
            const float4 xv = *(const float4*)&xs[rbase + r][kk * 4];
            acc[r] = fmaf(xv.x, wv.x, acc[r]);
            acc[r] = fmaf(xv.y, wv.y, acc[r]);
            acc[r] = fmaf(xv.z, wv.z, acc[r]);
            acc[r] = fmaf(xv.w, wv.w, acc[r]);
        }
    }

#pragma unroll
    for (int r = 0; r < 16; ++r) {
        const int row = row0 + rbase + r;
        if (row < N_NODES)
            h_bf[(size_t)row * HF + c] = __float2bfloat16(acc[r]);
    }

    {   // scores: thread -> (row = t&31, head, src/dst)
        const int r = t & 31;
        const int head = (t >> 5) & 3;
        const int which = t >> 7;
        const float4* pv4 = (const float4*)((which ? p_dst : p_src) + head * 128);
        float s = 0.f;
#pragma unroll 8
        for (int k4 = 0; k4 < 32; ++k4) {
            const float4 xv = *(const float4*)&xs[r][k4 * 4];
            const float4 p4 = pv4[k4];
            s = fmaf(xv.x, p4.x, s); s = fmaf(xv.y, p4.y, s);
            s = fmaf(xv.z, p4.z, s); s = fmaf(xv.w, p4.w, s);
        }
        const int row = row0 + r;
        if (row < N_NODES) {
            if (which == 0) ssrc[row * NHEAD + head] = s;
            else            sdst[row * NHEAD + head] = s;
        }
    }
}

// ---------------------------------------------------------------------------
// CSR build, pass 1: block-reserved bucket binning. Each block handles a
// 4096-edge chunk: LDS histogram over 196 buckets (dst>>8), ONE global
// atomic per (block,bucket) to reserve a contiguous run, then writes packed
// (dlocal<<16 | src) words into its own run -> L2 write-combining works.
// ---------------------------------------------------------------------------
__global__ __launch_bounds__(256) void bucket_bin(
    const int* __restrict__ src, const int* __restrict__ dst,
    int* __restrict__ cursor, unsigned int* __restrict__ buf)
{
    __shared__ int hist[NB], base[NB], fill[NB];
    const int t = threadIdx.x;
    const int e0 = blockIdx.x * CHUNK;
    const int n = min(CHUNK, N_EDGES - e0);

    for (int b = t; b < NB; b += 256) { hist[b] = 0; fill[b] = 0; }
    __syncthreads();

    for (int i = t; i < n; i += 256)
        atomicAdd(&hist[dst[e0 + i] >> 8], 1);
    __syncthreads();

    for (int b = t; b < NB; b += 256)
        base[b] = hist[b] ? atomicAdd(&cursor[b], hist[b]) : 0;
    __syncthreads();

    for (int i = t; i < n; i += 256) {
        const int d = dst[e0 + i];
        const int b = d >> 8;
        const int slot = base[b] + atomicAdd(&fill[b], 1);
        buf[b * BCAP + slot] = (unsigned)src[e0 + i] | ((unsigned)(d & 255) << 16);
    }
}

// ---------------------------------------------------------------------------
// CSR build, pass 2a: exclusive scan of the 196 bucket counts -> bases.
// ---------------------------------------------------------------------------
__global__ __launch_bounds__(256) void bucket_scan(
    const int* __restrict__ cursor, int* __restrict__ bbase,
    int* __restrict__ offs)
{
    __shared__ int tmp[256];
    const int t = threadIdx.x;
    const int v = (t < NB) ? cursor[t] : 0;
    tmp[t] = v;
    __syncthreads();
#pragma unroll
    for (int off = 1; off < 256; off <<= 1) {
        const int a = (t >= off) ? tmp[t - off] : 0;
        __syncthreads();
        tmp[t] += a;
        __syncthreads();
    }
    if (t < NB) bbase[t] = tmp[t] - v;
    if (t == 0) offs[N_NODES] = N_EDGES;
}

// ---------------------------------------------------------------------------
// CSR build, pass 2b: one block per bucket. LDS histogram over the 256
// bucket-local dsts, LDS scan -> offs[] (global CSR offsets), then scatter
// src ids into the block's contiguous csr region (LDS fill counters only).
// ---------------------------------------------------------------------------
__global__ __launch_bounds__(256) void csr_build(
    const unsigned int* __restrict__ buf, const int* __restrict__ cursor,
    const int* __restrict__ bbase, int* __restrict__ offs,
    int* __restrict__ csr_src)
{
    __shared__ int h2[256], loc[256], tmp[256];
    const int b = blockIdx.x;
    const int t = threadIdx.x;
    const int cnt = cursor[b];
    const int base = bbase[b];
    const unsigned int* bb = buf + b * BCAP;

    h2[t] = 0;
    __syncthreads();
    for (int i = t; i < cnt; i += 256)
        atomicAdd(&h2[bb[i] >> 16], 1);
    __syncthreads();

    tmp[t] = h2[t];
    __syncthreads();
#pragma unroll
    for (int off = 1; off < 256; off <<= 1) {
        const int a = (t >= off) ? tmp[t - off] : 0;
        __syncthreads();
        tmp[t] += a;
        __syncthreads();
    }
    loc[t] = tmp[t] - h2[t];
    __syncthreads();

    const int d = (b << 8) + t;
    if (d < N_NODES) offs[d] = base + loc[t];

    h2[t] = loc[t];          // reuse as fill counters
    __syncthreads();

    for (int i = t; i < cnt; i += 256) {
        const unsigned int p = bb[i];
        const int pos = base + atomicAdd(&h2[p >> 16], 1);
        csr_src[pos] = (int)(p & 0xFFFFu);
    }
}

// ---------------------------------------------------------------------------
// Aggregation (gather, no atomics), vectorized: one block (128 thr = 2
// waves) per dst node. Lane l of each wave owns the feature PAIR (2l, 2l+1)
// — loaded as one uint (2x bf16, 4 B) instead of two scalar 2 B loads.
// Wave w processes edges i == w (mod 2); cross-wave partials (acc0, acc1,
// wsum) combine once via LDS at the end. Edge weights (4 exps/edge) staged
// in LDS as before. Output written by wave 0 as coalesced float2 with fused
// ELU. No segment-max needed: |e| bounded ~3, softmax shift-invariant.
// ---------------------------------------------------------------------------
__global__ __launch_bounds__(128) void gat_aggregate(
    const int* __restrict__ offs,
    const int* __restrict__ csr_src,
    const __hip_bfloat16* __restrict__ h_bf,
    const float4* __restrict__ ssrc4,
    const float4* __restrict__ sdst4,
    float* __restrict__ out)
{
    const int d = blockIdx.x;
    const int t = threadIdx.x;
    const int w = t >> 6;            // wave 0/1
    const int lane = t & 63;
    const int head = lane >> 4;      // features 2*lane, 2*lane+1 share head
    const int beg = offs[d], end = offs[d + 1];
    const float4 sd = sdst4[d];

    __shared__ int sids[128];
    __shared__ float wls[128 * 4];
    __shared__ float comb[64][3];

    float a0 = 0.f, a1 = 0.f, ws = 0.f;

    for (int base = beg; base < end; base += 128) {
        const int m = min(128, end - base);
        __syncthreads();
        if (t < m) {
            const int s = csr_src[base + t];
            sids[t] = s;
            const float4 ss = ssrc4[s];
            float e0 = ss.x + sd.x, e1 = ss.y + sd.y;
            float e2 = ss.z + sd.z, e3 = ss.w + sd.w;
            e0 = e0 > 0.f ? e0 : ALPHA * e0;
            e1 = e1 > 0.f ? e1 : ALPHA * e1;
            e2 = e2 > 0.f ? e2 : ALPHA * e2;
            e3 = e3 > 0.f ? e3 : ALPHA * e3;
            wls[t * 4 + 0] = __expf(e0);
            wls[t * 4 + 1] = __expf(e1);
            wls[t * 4 + 2] = __expf(e2);
            wls[t * 4 + 3] = __expf(e3);
        }
        __syncthreads();

        // wave w handles edges w, w+2, ... ; unrolled 2 (stride 4)
        int i = w;
        for (; i + 2 < m; i += 4) {
            const int sA = sids[i], sB = sids[i + 2];
            const float wA = wls[i * 4 + head];
            const float wB = wls[(i + 2) * 4 + head];
            const unsigned hA = *(const unsigned*)(h_bf + (size_t)sA * HF + lane * 2);
            const unsigned hB = *(const unsigned*)(h_bf + (size_t)sB * HF + lane * 2);
            a0 = fmaf(wA, __uint_as_float(hA << 16), a0);
            a1 = fmaf(wA, __uint_as_float(hA & 0xffff0000u), a1);
            a0 = fmaf(wB, __uint_as_float(hB << 16), a0);
            a1 = fmaf(wB, __uint_as_float(hB & 0xffff0000u), a1);
            ws += wA + wB;
        }
        for (; i < m; i += 2) {
            const int s = sids[i];
            const float wgt = wls[i * 4 + head];
            const unsigned hv = *(const unsigned*)(h_bf + (size_t)s * HF + lane * 2);
            a0 = fmaf(wgt, __uint_as_float(hv << 16), a0);
            a1 = fmaf(wgt, __uint_as_float(hv & 0xffff0000u), a1);
            ws += wgt;
        }
    }

    // cross-wave combine, then wave 0 writes out (coalesced float2)
    if (w == 1) { comb[lane][0] = a0; comb[lane][1] = a1; comb[lane][2] = ws; }
    __syncthreads();
    if (w == 0) {
        a0 += comb[lane][0]; a1 += comb[lane][1]; ws += comb[lane][2];
        float v0 = (ws > 0.f) ? a0 / ws : 0.f;
        float v1 = (ws > 0.f) ? a1 / ws : 0.f;
        v0 = v0 > 0.f ? v0 : expm1f(v0);
        v1 = v1 > 0.f ? v1 : expm1f(v1);
        *(float2*)(out + (size_t)d * HF + lane * 2) = make_float2(v0, v1);
    }
}

// ---------------------------------------------------------------------------
extern "C" void kernel_launch(void* const* d_in, const int* in_sizes, int n_in,
                              void* d_out, int out_size, void* d_ws, size_t ws_size,
                              hipStream_t stream)
{
    const float* x     = (const float*)d_in[0];
    const int*   ei    = (const int*)d_in[1];   // [2][E]
    const float* W     = (const float*)d_in[2];
    const float* a_src = (const float*)d_in[3];
    const float* a_dst = (const float*)d_in[4];
    float* out = (float*)d_out;

    char* ws = (char*)d_ws;
    __hip_bfloat16* h_bf = (__hip_bfloat16*)(ws);     // 12,800,000 B
    float* ssrc    = (float*)(ws + 12800000);         //    800,000 B
    float* sdst    = (float*)(ws + 13600000);         //    800,000 B
    int*   offs    = (int*)  (ws + 14400000);         //    200,016 B
    float* Wt      = (float*)(ws + 14600016);         //     65,536 B
    float* p_src   = (float*)(ws + 14665552);         //      2,048 B
    float* p_dst   = (float*)(ws + 14667600);         //      2,048 B
    int*   cursor  = (int*)  (ws + 14669648);         //        784 B
    int*   bbase   = (int*)  (ws + 14670432);         //        784 B
    unsigned int* bbuf = (unsigned int*)(ws + 14671216); // 7,225,344 B
    int*   csr_src = (int*)  (ws + 21896560);         //  6,400,000 B -> 28.3 MB

    const int* src = ei;
    const int* dst = ei + N_EDGES;

    hipMemsetAsync(cursor, 0, NB * sizeof(int), stream);

    gat_prep<<<2, 256, 0, stream>>>(W, a_src, a_dst, Wt, p_src, p_dst);

    gat_gemm_scores<<<NBLK_GEMM, 256, 0, stream>>>(
        x, Wt, p_src, p_dst, h_bf, ssrc, sdst);

    bucket_bin<<<NCHUNK, 256, 0, stream>>>(src, dst, cursor, bbuf);
    bucket_scan<<<1, 256, 0, stream>>>(cursor, bbase, offs);
    csr_build<<<NB, 256, 0, stream>>>(bbuf, cursor, bbase, offs, csr_src);

    gat_aggregate<<<N_NODES, HF, 0, stream>>>(
        offs, csr_src, h_bf, (const float4*)ssrc, (const float4*)sdst, out);
}